// Round 1
// baseline (285.108 us; speedup 1.0000x reference)
//
#include <hip/hip_runtime.h>
#include <hip/hip_bf16.h>
#include <math.h>

// Problem constants
#define BB 8
#define SS 1024
#define INDIM 512
#define ED 512
#define NH 8
#define HD 64

typedef __attribute__((ext_vector_type(8))) short short8;
typedef __attribute__((ext_vector_type(4))) float f32x4;
typedef unsigned short u16;

static __device__ __forceinline__ u16 f2bf(float f) {
  union { float f; unsigned u; } v; v.f = f;
  unsigned r = v.u + 0x7fffu + ((v.u >> 16) & 1u);
  return (u16)(r >> 16);
}

// ---------------- fp32 -> bf16 convert ----------------
__global__ void cvt_f32_bf16(const float* __restrict__ in, u16* __restrict__ out, int n4) {
  int i = blockIdx.x * blockDim.x + threadIdx.x;
  int stride = gridDim.x * blockDim.x;
  for (; i < n4; i += stride) {
    float4 v = ((const float4*)in)[i];
    ushort4 o;
    o.x = f2bf(v.x); o.y = f2bf(v.y); o.z = f2bf(v.z); o.w = f2bf(v.w);
    ((ushort4*)out)[i] = o;
  }
}

// ---------------- NT GEMM: C[M,N] = A[M,K] * B[N,K]^T (bf16 in, MFMA) -------
// EPI==0: QKV projection epilogue -> scatter to q (x0.125), k, vt layouts
// EPI==1: plain fp32 output (O projection)
template<int EPI>
__global__ __launch_bounds__(256, 2)
void gemm_nt(const u16* __restrict__ A, const u16* __restrict__ Bm, int K,
             float* __restrict__ outF,
             u16* __restrict__ qws, u16* __restrict__ kws, u16* __restrict__ vtws)
{
  __shared__ u16 As[128][72];
  __shared__ u16 Bs[128][72];
  const int tid = threadIdx.x;
  const int lane = tid & 63;
  const int wv = tid >> 6;
  const int wr = wv >> 1, wc = wv & 1;
  const int bm = blockIdx.x, bn = blockIdx.y;
  const int l15 = lane & 15, lg = lane >> 4;

  f32x4 acc[4][4];
  #pragma unroll
  for (int i = 0; i < 4; i++)
    #pragma unroll
    for (int j = 0; j < 4; j++) acc[i][j] = (f32x4){0.f, 0.f, 0.f, 0.f};

  for (int kk = 0; kk < K; kk += 64) {
    #pragma unroll
    for (int t = 0; t < 4; t++) {
      int ci = tid + t * 256;
      int row = ci >> 3, col = (ci & 7) * 8;
      uint4 va = *(const uint4*)(A + (size_t)(bm * 128 + row) * K + kk + col);
      *(uint4*)&As[row][col] = va;
      uint4 vb = *(const uint4*)(Bm + (size_t)(bn * 128 + row) * K + kk + col);
      *(uint4*)&Bs[row][col] = vb;
    }
    __syncthreads();
    #pragma unroll
    for (int kc = 0; kc < 2; kc++) {
      short8 af[4], bf[4];
      #pragma unroll
      for (int mi = 0; mi < 4; mi++)
        af[mi] = *(const short8*)&As[wr * 64 + mi * 16 + l15][kc * 32 + lg * 8];
      #pragma unroll
      for (int ni = 0; ni < 4; ni++)
        bf[ni] = *(const short8*)&Bs[wc * 64 + ni * 16 + l15][kc * 32 + lg * 8];
      #pragma unroll
      for (int mi = 0; mi < 4; mi++)
        #pragma unroll
        for (int ni = 0; ni < 4; ni++)
          acc[mi][ni] = __builtin_amdgcn_mfma_f32_16x16x32_bf16(af[mi], bf[ni], acc[mi][ni], 0, 0, 0);
    }
    __syncthreads();
  }

  // epilogue; C-frag: col = lane&15, row = (lane>>4)*4 + r
  #pragma unroll
  for (int mi = 0; mi < 4; mi++) {
    int rowg = bm * 128 + wr * 64 + mi * 16 + lg * 4;
    #pragma unroll
    for (int ni = 0; ni < 4; ni++) {
      int colg = bn * 128 + wc * 64 + ni * 16 + l15;
      #pragma unroll
      for (int r = 0; r < 4; r++) {
        int rg = rowg + r;
        float v = acc[mi][ni][r];
        if (EPI == 0) {
          int b = rg >> 10, s = rg & 1023;
          int h = colg / 192, c = colg - h * 192;
          int bh = b * 8 + h;
          if (c < 64)
            qws[((size_t)(bh * 1024 + s)) * 64 + c] = f2bf(v * 0.125f);
          else if (c < 128)
            kws[((size_t)(bh * 1024 + s)) * 64 + (c - 64)] = f2bf(v);
          else
            vtws[((size_t)(bh * 64 + (c - 128))) * 1024 + s] = f2bf(v);
        } else {
          outF[(size_t)rg * 512 + colg] = v;
        }
      }
    }
  }
}

// ---------------- Flash attention ----------------
// grid: 1024 blocks = (b,h) * 16 q-tiles of 64 rows; 4 waves, each 16 q rows
__global__ __launch_bounds__(256, 2)
void attn_kernel(const u16* __restrict__ qws, const u16* __restrict__ kws,
                 const u16* __restrict__ vtws, u16* __restrict__ vals)
{
  __shared__ u16 Ksm[64][72];
  __shared__ u16 Vsm[64][72];
  __shared__ u16 Psm[4][16][72];
  const int tid = threadIdx.x;
  const int lane = tid & 63;
  const int wv = tid >> 6;
  const int l15 = lane & 15, lg = lane >> 4;
  const int bh = blockIdx.x >> 4;
  const int qt = blockIdx.x & 15;
  const int q0 = qt * 64;

  // stage Q tile into Ksm, pull A-frags to regs
  #pragma unroll
  for (int t = 0; t < 2; t++) {
    int ci = tid + t * 256;
    int row = ci >> 3, col = (ci & 7) * 8;
    *(uint4*)&Ksm[row][col] = *(const uint4*)(qws + ((size_t)bh * 1024 + q0 + row) * 64 + col);
  }
  __syncthreads();
  short8 qf[2];
  qf[0] = *(const short8*)&Ksm[wv * 16 + l15][lg * 8];
  qf[1] = *(const short8*)&Ksm[wv * 16 + l15][32 + lg * 8];

  f32x4 o[4];
  #pragma unroll
  for (int i = 0; i < 4; i++) o[i] = (f32x4){0.f, 0.f, 0.f, 0.f};
  float m[4], l[4];
  #pragma unroll
  for (int r = 0; r < 4; r++) { m[r] = -INFINITY; l[r] = 0.f; }

  for (int kv = 0; kv < 1024; kv += 64) {
    __syncthreads();
    #pragma unroll
    for (int t = 0; t < 2; t++) {
      int ci = tid + t * 256;
      int row = ci >> 3, col = (ci & 7) * 8;
      *(uint4*)&Ksm[row][col] = *(const uint4*)(kws + ((size_t)bh * 1024 + kv + row) * 64 + col);
      *(uint4*)&Vsm[row][col] = *(const uint4*)(vtws + ((size_t)(bh * 64 + row)) * 1024 + kv + col);
    }
    __syncthreads();

    // S = Q K^T (M=16 q, N=64 keys as 4 frags, K=64 dims as 2 chunks)
    f32x4 sf[4];
    #pragma unroll
    for (int f = 0; f < 4; f++) {
      short8 k0 = *(const short8*)&Ksm[f * 16 + l15][lg * 8];
      short8 k1 = *(const short8*)&Ksm[f * 16 + l15][32 + lg * 8];
      f32x4 c = (f32x4){0.f, 0.f, 0.f, 0.f};
      c = __builtin_amdgcn_mfma_f32_16x16x32_bf16(qf[0], k0, c, 0, 0, 0);
      c = __builtin_amdgcn_mfma_f32_16x16x32_bf16(qf[1], k1, c, 0, 0, 0);
      sf[f] = c;
    }

    // online softmax; lane holds rows lg*4+r, key cols l15+16f
    float al[4];
    #pragma unroll
    for (int r = 0; r < 4; r++) {
      float rm = fmaxf(fmaxf(sf[0][r], sf[1][r]), fmaxf(sf[2][r], sf[3][r]));
      #pragma unroll
      for (int off = 1; off < 16; off <<= 1) rm = fmaxf(rm, __shfl_xor(rm, off));
      float mn = fmaxf(m[r], rm);
      al[r] = __expf(m[r] - mn);
      m[r] = mn;
      float rs = 0.f;
      #pragma unroll
      for (int f = 0; f < 4; f++) {
        float p = __expf(sf[f][r] - mn);
        sf[f][r] = p;
        rs += p;
      }
      #pragma unroll
      for (int off = 1; off < 16; off <<= 1) rs += __shfl_xor(rs, off);
      l[r] = l[r] * al[r] + rs;
    }

    // P -> per-wave LDS (A-operand layout round trip)
    #pragma unroll
    for (int f = 0; f < 4; f++)
      #pragma unroll
      for (int r = 0; r < 4; r++)
        Psm[wv][lg * 4 + r][f * 16 + l15] = f2bf(sf[f][r]);
    asm volatile("s_waitcnt lgkmcnt(0)" ::: "memory");

    // rescale O
    #pragma unroll
    for (int dn = 0; dn < 4; dn++)
      #pragma unroll
      for (int r = 0; r < 4; r++)
        o[dn][r] *= al[r];

    // O += P V  (A = P [16 x 64keys], B = Vt tile)
    short8 pf[2];
    pf[0] = *(const short8*)&Psm[wv][l15][lg * 8];
    pf[1] = *(const short8*)&Psm[wv][l15][32 + lg * 8];
    #pragma unroll
    for (int dn = 0; dn < 4; dn++) {
      short8 v0 = *(const short8*)&Vsm[dn * 16 + l15][lg * 8];
      short8 v1 = *(const short8*)&Vsm[dn * 16 + l15][32 + lg * 8];
      o[dn] = __builtin_amdgcn_mfma_f32_16x16x32_bf16(pf[0], v0, o[dn], 0, 0, 0);
      o[dn] = __builtin_amdgcn_mfma_f32_16x16x32_bf16(pf[1], v1, o[dn], 0, 0, 0);
    }
  }

  // write vals[b, s, h*64+d] bf16
  const int b = bh >> 3, h = bh & 7;
  #pragma unroll
  for (int r = 0; r < 4; r++) {
    float inv = 1.f / l[r];
    int qrow = q0 + wv * 16 + lg * 4 + r;
    #pragma unroll
    for (int dn = 0; dn < 4; dn++) {
      int col = h * 64 + dn * 16 + l15;
      vals[((size_t)(b * 1024 + qrow)) * 512 + col] = f2bf(o[dn][r] * inv);
    }
  }
}

// ---------------- LayerNorm over (S,E) per batch ----------------
__global__ void ln_stats(const float* __restrict__ o, float* __restrict__ stats) {
  const int b = blockIdx.x;
  const float* p = o + (size_t)b * 524288;
  float s1 = 0.f, s2 = 0.f;
  for (int i = threadIdx.x; i < 131072; i += 256) {
    float4 v = ((const float4*)p)[i];
    s1 += v.x + v.y + v.z + v.w;
    s2 += v.x * v.x + v.y * v.y + v.z * v.z + v.w * v.w;
  }
  #pragma unroll
  for (int off = 1; off < 64; off <<= 1) { s1 += __shfl_xor(s1, off); s2 += __shfl_xor(s2, off); }
  __shared__ float p1[4], p2[4];
  int wv = threadIdx.x >> 6;
  if ((threadIdx.x & 63) == 0) { p1[wv] = s1; p2[wv] = s2; }
  __syncthreads();
  if (threadIdx.x == 0) {
    float t1 = p1[0] + p1[1] + p1[2] + p1[3];
    float t2 = p2[0] + p2[1] + p2[2] + p2[3];
    float mu = t1 / 524288.f;
    float var = t2 / 524288.f - mu * mu;
    stats[b * 2] = mu;
    stats[b * 2 + 1] = rsqrtf(var + 1e-5f);
  }
}

__global__ void ln_norm(float* __restrict__ o, const float* __restrict__ stats) {
  int i = blockIdx.x * blockDim.x + threadIdx.x;
  int stride = gridDim.x * blockDim.x;
  for (; i < 1048576; i += stride) {
    int b = i >> 17;  // 131072 float4 per batch
    float mu = stats[b * 2], rs = stats[b * 2 + 1];
    float4 v = ((float4*)o)[i];
    v.x = (v.x - mu) * rs; v.y = (v.y - mu) * rs;
    v.z = (v.z - mu) * rs; v.w = (v.w - mu) * rs;
    ((float4*)o)[i] = v;
  }
}

extern "C" void kernel_launch(void* const* d_in, const int* in_sizes, int n_in,
                              void* d_out, int out_size, void* d_ws, size_t ws_size,
                              hipStream_t stream) {
  const float* x = (const float*)d_in[0];
  const float* wqkv = (const float*)d_in[1];
  const float* wo = (const float*)d_in[2];
  float* out = (float*)d_out;
  char* ws = (char*)d_ws;

  u16* xb    = (u16*)(ws + 0);          // 8192*512   bf16 =  8,388,608 B
  u16* wqb   = (u16*)(ws + 8388608);    // 1536*512   bf16 =  1,572,864 B
  u16* wob   = (u16*)(ws + 9961472);    // 512*512    bf16 =    524,288 B
  u16* qws   = (u16*)(ws + 10485760);   // [bh,1024,64]    =  8,388,608 B
  u16* kws   = (u16*)(ws + 18874368);   // [bh,1024,64]    =  8,388,608 B
  u16* vtws  = (u16*)(ws + 27262976);   // [bh,64,1024]    =  8,388,608 B
  u16* vals  = (u16*)(ws + 35651584);   // [8192,512] bf16 =  8,388,608 B
  float* st  = (float*)(ws + 44040192); // 16 floats

  cvt_f32_bf16<<<1024, 256, 0, stream>>>(x, xb, 4194304 / 4);
  cvt_f32_bf16<<<256, 256, 0, stream>>>(wqkv, wqb, 786432 / 4);
  cvt_f32_bf16<<<128, 256, 0, stream>>>(wo, wob, 262144 / 4);

  dim3 g1(64, 12);
  gemm_nt<0><<<g1, 256, 0, stream>>>(xb, wqb, 512, nullptr, qws, kws, vtws);

  attn_kernel<<<1024, 256, 0, stream>>>(qws, kws, vtws, vals);

  dim3 g2(64, 4);
  gemm_nt<1><<<g2, 256, 0, stream>>>(vals, wob, 512, out, nullptr, nullptr, nullptr);

  ln_stats<<<8, 256, 0, stream>>>(out, st);
  ln_norm<<<2048, 256, 0, stream>>>(out, st);
}

// Round 2
// 124.617 us; speedup vs baseline: 2.2879x; 2.2879x over previous
//
#include <hip/hip_runtime.h>
#include <hip/hip_bf16.h>
#include <math.h>

// Problem constants
#define BB 8
#define SS 1024
#define INDIM 512
#define ED 512
#define NH 8
#define HD 64

typedef __attribute__((ext_vector_type(8))) short short8;
typedef __attribute__((ext_vector_type(4))) float f32x4;
typedef unsigned short u16;

static __device__ __forceinline__ u16 f2bf(float f) {
  union { float f; unsigned u; } v; v.f = f;
  unsigned r = v.u + 0x7fffu + ((v.u >> 16) & 1u);
  return (u16)(r >> 16);
}

// ---------------- fp32 -> bf16 convert (all three inputs, one launch) ------
__global__ void cvt_all(const float* __restrict__ x, const float* __restrict__ wq,
                        const float* __restrict__ wo, u16* __restrict__ xb,
                        u16* __restrict__ wqb, u16* __restrict__ wob) {
  const int n1 = 1048576;            // x: 4194304/4 quads
  const int n2 = n1 + 196608;        // wqkv: 786432/4
  const int n3 = n2 + 65536;         // wo: 262144/4
  int i = blockIdx.x * blockDim.x + threadIdx.x;
  int stride = gridDim.x * blockDim.x;
  for (; i < n3; i += stride) {
    const float4* src; ushort4* dst; int j;
    if (i < n1)      { src = (const float4*)x;  dst = (ushort4*)xb;  j = i; }
    else if (i < n2) { src = (const float4*)wq; dst = (ushort4*)wqb; j = i - n1; }
    else             { src = (const float4*)wo; dst = (ushort4*)wob; j = i - n2; }
    float4 v = src[j];
    ushort4 o;
    o.x = f2bf(v.x); o.y = f2bf(v.y); o.z = f2bf(v.z); o.w = f2bf(v.w);
    dst[j] = o;
  }
}

// ---------------- NT GEMM: C[M,N] = A[M,K] * B[N,K]^T (bf16 in, MFMA) -------
// EPI==0: QKV projection epilogue -> scatter to q (x0.125), k, vt layouts
// EPI==1: fp32 output (O projection) + per-block LN partial stats
template<int EPI>
__global__ __launch_bounds__(256, 2)
void gemm_nt(const u16* __restrict__ A, const u16* __restrict__ Bm, int K,
             float* __restrict__ outF,
             u16* __restrict__ qws, u16* __restrict__ kws, u16* __restrict__ vtws,
             float2* __restrict__ partials)
{
  __shared__ u16 As[128][72];
  __shared__ u16 Bs[128][72];
  const int tid = threadIdx.x;
  const int lane = tid & 63;
  const int wv = tid >> 6;
  const int wr = wv >> 1, wc = wv & 1;
  const int bm = blockIdx.x, bn = blockIdx.y;
  const int l15 = lane & 15, lg = lane >> 4;

  f32x4 acc[4][4];
  #pragma unroll
  for (int i = 0; i < 4; i++)
    #pragma unroll
    for (int j = 0; j < 4; j++) acc[i][j] = (f32x4){0.f, 0.f, 0.f, 0.f};

  for (int kk = 0; kk < K; kk += 64) {
    #pragma unroll
    for (int t = 0; t < 4; t++) {
      int ci = tid + t * 256;
      int row = ci >> 3, col = (ci & 7) * 8;
      uint4 va = *(const uint4*)(A + (size_t)(bm * 128 + row) * K + kk + col);
      *(uint4*)&As[row][col] = va;
      uint4 vb = *(const uint4*)(Bm + (size_t)(bn * 128 + row) * K + kk + col);
      *(uint4*)&Bs[row][col] = vb;
    }
    __syncthreads();
    #pragma unroll
    for (int kc = 0; kc < 2; kc++) {
      short8 af[4], bf[4];
      #pragma unroll
      for (int mi = 0; mi < 4; mi++)
        af[mi] = *(const short8*)&As[wr * 64 + mi * 16 + l15][kc * 32 + lg * 8];
      #pragma unroll
      for (int ni = 0; ni < 4; ni++)
        bf[ni] = *(const short8*)&Bs[wc * 64 + ni * 16 + l15][kc * 32 + lg * 8];
      #pragma unroll
      for (int mi = 0; mi < 4; mi++)
        #pragma unroll
        for (int ni = 0; ni < 4; ni++)
          acc[mi][ni] = __builtin_amdgcn_mfma_f32_16x16x32_bf16(af[mi], bf[ni], acc[mi][ni], 0, 0, 0);
    }
    __syncthreads();
  }

  // epilogue; C-frag: col = lane&15, row = (lane>>4)*4 + r
  #pragma unroll
  for (int mi = 0; mi < 4; mi++) {
    int rowg = bm * 128 + wr * 64 + mi * 16 + lg * 4;
    #pragma unroll
    for (int ni = 0; ni < 4; ni++) {
      int colg = bn * 128 + wc * 64 + ni * 16 + l15;
      #pragma unroll
      for (int r = 0; r < 4; r++) {
        int rg = rowg + r;
        float v = acc[mi][ni][r];
        if (EPI == 0) {
          int b = rg >> 10, s = rg & 1023;
          int h = colg / 192, c = colg - h * 192;
          int bh = b * 8 + h;
          if (c < 64)
            qws[((size_t)(bh * 1024 + s)) * 64 + c] = f2bf(v * 0.125f);
          else if (c < 128)
            kws[((size_t)(bh * 1024 + s)) * 64 + (c - 64)] = f2bf(v);
          else
            vtws[((size_t)(bh * 64 + (c - 128))) * 1024 + s] = f2bf(v);
        } else {
          outF[(size_t)rg * 512 + colg] = v;
        }
      }
    }
  }

  if (EPI == 1) {
    // per-block LN partial stats (block tile lies within one batch)
    float s1 = 0.f, s2 = 0.f;
    #pragma unroll
    for (int mi = 0; mi < 4; mi++)
      #pragma unroll
      for (int ni = 0; ni < 4; ni++)
        #pragma unroll
        for (int r = 0; r < 4; r++) {
          float v = acc[mi][ni][r];
          s1 += v; s2 += v * v;
        }
    #pragma unroll
    for (int off = 1; off < 64; off <<= 1) {
      s1 += __shfl_xor(s1, off);
      s2 += __shfl_xor(s2, off);
    }
    __shared__ float r1[4], r2[4];
    if (lane == 0) { r1[wv] = s1; r2[wv] = s2; }
    __syncthreads();
    if (tid == 0) {
      float t1 = r1[0] + r1[1] + r1[2] + r1[3];
      float t2 = r2[0] + r2[1] + r2[2] + r2[3];
      partials[bm * 4 + bn] = make_float2(t1, t2);
    }
  }
}

// ---------------- Flash attention ----------------
// grid: 1024 blocks = (b,h) * 16 q-tiles of 64 rows; 4 waves, each 16 q rows
__global__ __launch_bounds__(256, 2)
void attn_kernel(const u16* __restrict__ qws, const u16* __restrict__ kws,
                 const u16* __restrict__ vtws, u16* __restrict__ vals)
{
  __shared__ u16 Ksm[64][72];
  __shared__ u16 Vsm[64][72];
  __shared__ u16 Psm[4][16][72];
  const int tid = threadIdx.x;
  const int lane = tid & 63;
  const int wv = tid >> 6;
  const int l15 = lane & 15, lg = lane >> 4;
  const int bh = blockIdx.x >> 4;
  const int qt = blockIdx.x & 15;
  const int q0 = qt * 64;

  // stage Q tile into Ksm, pull A-frags to regs
  #pragma unroll
  for (int t = 0; t < 2; t++) {
    int ci = tid + t * 256;
    int row = ci >> 3, col = (ci & 7) * 8;
    *(uint4*)&Ksm[row][col] = *(const uint4*)(qws + ((size_t)bh * 1024 + q0 + row) * 64 + col);
  }
  __syncthreads();
  short8 qf[2];
  qf[0] = *(const short8*)&Ksm[wv * 16 + l15][lg * 8];
  qf[1] = *(const short8*)&Ksm[wv * 16 + l15][32 + lg * 8];

  f32x4 o[4];
  #pragma unroll
  for (int i = 0; i < 4; i++) o[i] = (f32x4){0.f, 0.f, 0.f, 0.f};
  float m[4], l[4];
  #pragma unroll
  for (int r = 0; r < 4; r++) { m[r] = -INFINITY; l[r] = 0.f; }

  for (int kv = 0; kv < 1024; kv += 64) {
    __syncthreads();
    #pragma unroll
    for (int t = 0; t < 2; t++) {
      int ci = tid + t * 256;
      int row = ci >> 3, col = (ci & 7) * 8;
      *(uint4*)&Ksm[row][col] = *(const uint4*)(kws + ((size_t)bh * 1024 + kv + row) * 64 + col);
      *(uint4*)&Vsm[row][col] = *(const uint4*)(vtws + ((size_t)(bh * 64 + row)) * 1024 + kv + col);
    }
    __syncthreads();

    // S = Q K^T (M=16 q, N=64 keys as 4 frags, K=64 dims as 2 chunks)
    f32x4 sf[4];
    #pragma unroll
    for (int f = 0; f < 4; f++) {
      short8 k0 = *(const short8*)&Ksm[f * 16 + l15][lg * 8];
      short8 k1 = *(const short8*)&Ksm[f * 16 + l15][32 + lg * 8];
      f32x4 c = (f32x4){0.f, 0.f, 0.f, 0.f};
      c = __builtin_amdgcn_mfma_f32_16x16x32_bf16(qf[0], k0, c, 0, 0, 0);
      c = __builtin_amdgcn_mfma_f32_16x16x32_bf16(qf[1], k1, c, 0, 0, 0);
      sf[f] = c;
    }

    // online softmax; lane holds rows lg*4+r, key cols l15+16f
    float al[4];
    #pragma unroll
    for (int r = 0; r < 4; r++) {
      float rm = fmaxf(fmaxf(sf[0][r], sf[1][r]), fmaxf(sf[2][r], sf[3][r]));
      #pragma unroll
      for (int off = 1; off < 16; off <<= 1) rm = fmaxf(rm, __shfl_xor(rm, off));
      float mn = fmaxf(m[r], rm);
      al[r] = __expf(m[r] - mn);
      m[r] = mn;
      float rs = 0.f;
      #pragma unroll
      for (int f = 0; f < 4; f++) {
        float p = __expf(sf[f][r] - mn);
        sf[f][r] = p;
        rs += p;
      }
      #pragma unroll
      for (int off = 1; off < 16; off <<= 1) rs += __shfl_xor(rs, off);
      l[r] = l[r] * al[r] + rs;
    }

    // P -> per-wave LDS (A-operand layout round trip)
    #pragma unroll
    for (int f = 0; f < 4; f++)
      #pragma unroll
      for (int r = 0; r < 4; r++)
        Psm[wv][lg * 4 + r][f * 16 + l15] = f2bf(sf[f][r]);
    asm volatile("s_waitcnt lgkmcnt(0)" ::: "memory");

    // rescale O
    #pragma unroll
    for (int dn = 0; dn < 4; dn++)
      #pragma unroll
      for (int r = 0; r < 4; r++)
        o[dn][r] *= al[r];

    // O += P V  (A = P [16 x 64keys], B = Vt tile)
    short8 pf[2];
    pf[0] = *(const short8*)&Psm[wv][l15][lg * 8];
    pf[1] = *(const short8*)&Psm[wv][l15][32 + lg * 8];
    #pragma unroll
    for (int dn = 0; dn < 4; dn++) {
      short8 v0 = *(const short8*)&Vsm[dn * 16 + l15][lg * 8];
      short8 v1 = *(const short8*)&Vsm[dn * 16 + l15][32 + lg * 8];
      o[dn] = __builtin_amdgcn_mfma_f32_16x16x32_bf16(pf[0], v0, o[dn], 0, 0, 0);
      o[dn] = __builtin_amdgcn_mfma_f32_16x16x32_bf16(pf[1], v1, o[dn], 0, 0, 0);
    }
  }

  // write vals[b, s, h*64+d] bf16
  const int b = bh >> 3, h = bh & 7;
  #pragma unroll
  for (int r = 0; r < 4; r++) {
    float inv = 1.f / l[r];
    int qrow = q0 + wv * 16 + lg * 4 + r;
    #pragma unroll
    for (int dn = 0; dn < 4; dn++) {
      int col = h * 64 + dn * 16 + l15;
      vals[((size_t)(b * 1024 + qrow)) * 512 + col] = f2bf(o[dn][r] * inv);
    }
  }
}

// ---------------- LN finalize: reduce 32 partials per batch ----------------
__global__ void ln_fin(const float2* __restrict__ partials, float* __restrict__ stats) {
  const int b = blockIdx.x;      // 8 blocks, 64 threads
  const int t = threadIdx.x;
  float s1 = 0.f, s2 = 0.f;
  if (t < 32) {
    float2 p = partials[b * 32 + t];
    s1 = p.x; s2 = p.y;
  }
  #pragma unroll
  for (int off = 1; off < 64; off <<= 1) {
    s1 += __shfl_xor(s1, off);
    s2 += __shfl_xor(s2, off);
  }
  if (t == 0) {
    float mu = s1 / 524288.f;
    float var = s2 / 524288.f - mu * mu;
    stats[b * 2] = mu;
    stats[b * 2 + 1] = rsqrtf(var + 1e-5f);
  }
}

__global__ void ln_norm(float* __restrict__ o, const float* __restrict__ stats) {
  int i = blockIdx.x * blockDim.x + threadIdx.x;
  int stride = gridDim.x * blockDim.x;
  for (; i < 1048576; i += stride) {
    int b = i >> 17;  // 131072 float4 per batch
    float mu = stats[b * 2], rs = stats[b * 2 + 1];
    float4 v = ((float4*)o)[i];
    v.x = (v.x - mu) * rs; v.y = (v.y - mu) * rs;
    v.z = (v.z - mu) * rs; v.w = (v.w - mu) * rs;
    ((float4*)o)[i] = v;
  }
}

extern "C" void kernel_launch(void* const* d_in, const int* in_sizes, int n_in,
                              void* d_out, int out_size, void* d_ws, size_t ws_size,
                              hipStream_t stream) {
  const float* x = (const float*)d_in[0];
  const float* wqkv = (const float*)d_in[1];
  const float* wo = (const float*)d_in[2];
  float* out = (float*)d_out;
  char* ws = (char*)d_ws;

  u16* xb        = (u16*)(ws + 0);          // 8192*512   bf16 =  8,388,608 B
  u16* wqb       = (u16*)(ws + 8388608);    // 1536*512   bf16 =  1,572,864 B
  u16* wob       = (u16*)(ws + 9961472);    // 512*512    bf16 =    524,288 B
  u16* qws       = (u16*)(ws + 10485760);   // [bh,1024,64]    =  8,388,608 B
  u16* kws       = (u16*)(ws + 18874368);   // [bh,1024,64]    =  8,388,608 B
  u16* vtws      = (u16*)(ws + 27262976);   // [bh,64,1024]    =  8,388,608 B
  u16* vals      = (u16*)(ws + 35651584);   // [8192,512] bf16 =  8,388,608 B
  float* st      = (float*)(ws + 44040192); // 16 floats
  float2* parts  = (float2*)(ws + 44040256);// 256 float2 = 2 KB

  cvt_all<<<1280, 256, 0, stream>>>(x, wqkv, wo, xb, wqb, wob);

  dim3 g1(64, 12);
  gemm_nt<0><<<g1, 256, 0, stream>>>(xb, wqb, 512, nullptr, qws, kws, vtws, nullptr);

  attn_kernel<<<1024, 256, 0, stream>>>(qws, kws, vtws, vals);

  dim3 g2(64, 4);
  gemm_nt<1><<<g2, 256, 0, stream>>>(vals, wob, 512, out, nullptr, nullptr, nullptr, parts);

  ln_fin<<<8, 64, 0, stream>>>(parts, st);
  ln_norm<<<2048, 256, 0, stream>>>(out, st);
}

// Round 3
// 109.928 us; speedup vs baseline: 2.5936x; 1.1336x over previous
//
#include <hip/hip_runtime.h>
#include <hip/hip_bf16.h>
#include <math.h>

// Problem constants
#define BB 8
#define SS 1024
#define INDIM 512
#define ED 512
#define NH 8
#define HD 64

typedef __attribute__((ext_vector_type(8))) short short8;
typedef __attribute__((ext_vector_type(4))) float f32x4;
typedef unsigned short u16;

static __device__ __forceinline__ u16 f2bf(float f) {
  union { float f; unsigned u; } v; v.f = f;
  unsigned r = v.u + 0x7fffu + ((v.u >> 16) & 1u);
  return (u16)(r >> 16);
}

// packed f32x2 -> bf16x2 (RTNE), single VOP3 instr on gfx950
static __device__ __forceinline__ unsigned cvt_pk_bf16(float a, float b) {
  unsigned r;
  asm("v_cvt_pk_bf16_f32 %0, %1, %2" : "=v"(r) : "v"(a), "v"(b));
  return r;
}
// v_exp_f32 = 2^x natively
static __device__ __forceinline__ float fast_exp2(float x) {
  float r; asm("v_exp_f32 %0, %1" : "=v"(r) : "v"(x)); return r;
}

// ---------------- fp32 -> bf16 convert (all three inputs, one launch) ------
__global__ void cvt_all(const float* __restrict__ x, const float* __restrict__ wq,
                        const float* __restrict__ wo, u16* __restrict__ xb,
                        u16* __restrict__ wqb, u16* __restrict__ wob) {
  const int n1 = 1048576;            // x: 4194304/4 quads
  const int n2 = n1 + 196608;        // wqkv: 786432/4
  const int n3 = n2 + 65536;         // wo: 262144/4
  int i = blockIdx.x * blockDim.x + threadIdx.x;
  int stride = gridDim.x * blockDim.x;
  for (; i < n3; i += stride) {
    const float4* src; ushort4* dst; int j;
    if (i < n1)      { src = (const float4*)x;  dst = (ushort4*)xb;  j = i; }
    else if (i < n2) { src = (const float4*)wq; dst = (ushort4*)wqb; j = i - n1; }
    else             { src = (const float4*)wo; dst = (ushort4*)wob; j = i - n2; }
    float4 v = src[j];
    ushort4 o;
    o.x = f2bf(v.x); o.y = f2bf(v.y); o.z = f2bf(v.z); o.w = f2bf(v.w);
    dst[j] = o;
  }
}

// ---------------- NT GEMM: C[M,N] = A[M,K] * B[N,K]^T (bf16 in, MFMA) -------
// EPI==0: QKV projection epilogue -> scatter to q (x 0.125*log2e), k, vt layouts
// EPI==1: fp32 output (O projection) + per-block LN partial stats
template<int EPI>
__global__ __launch_bounds__(256, 2)
void gemm_nt(const u16* __restrict__ A, const u16* __restrict__ Bm, int K,
             float* __restrict__ outF,
             u16* __restrict__ qws, u16* __restrict__ kws, u16* __restrict__ vtws,
             float2* __restrict__ partials)
{
  __shared__ u16 As[128][72];
  __shared__ u16 Bs[128][72];
  const int tid = threadIdx.x;
  const int lane = tid & 63;
  const int wv = tid >> 6;
  const int wr = wv >> 1, wc = wv & 1;
  const int bm = blockIdx.x, bn = blockIdx.y;
  const int l15 = lane & 15, lg = lane >> 4;

  f32x4 acc[4][4];
  #pragma unroll
  for (int i = 0; i < 4; i++)
    #pragma unroll
    for (int j = 0; j < 4; j++) acc[i][j] = (f32x4){0.f, 0.f, 0.f, 0.f};

  for (int kk = 0; kk < K; kk += 64) {
    #pragma unroll
    for (int t = 0; t < 4; t++) {
      int ci = tid + t * 256;
      int row = ci >> 3, col = (ci & 7) * 8;
      uint4 va = *(const uint4*)(A + (size_t)(bm * 128 + row) * K + kk + col);
      *(uint4*)&As[row][col] = va;
      uint4 vb = *(const uint4*)(Bm + (size_t)(bn * 128 + row) * K + kk + col);
      *(uint4*)&Bs[row][col] = vb;
    }
    __syncthreads();
    #pragma unroll
    for (int kc = 0; kc < 2; kc++) {
      short8 af[4], bf[4];
      #pragma unroll
      for (int mi = 0; mi < 4; mi++)
        af[mi] = *(const short8*)&As[wr * 64 + mi * 16 + l15][kc * 32 + lg * 8];
      #pragma unroll
      for (int ni = 0; ni < 4; ni++)
        bf[ni] = *(const short8*)&Bs[wc * 64 + ni * 16 + l15][kc * 32 + lg * 8];
      #pragma unroll
      for (int mi = 0; mi < 4; mi++)
        #pragma unroll
        for (int ni = 0; ni < 4; ni++)
          acc[mi][ni] = __builtin_amdgcn_mfma_f32_16x16x32_bf16(af[mi], bf[ni], acc[mi][ni], 0, 0, 0);
    }
    __syncthreads();
  }

  // epilogue; C-frag: col = lane&15, row = (lane>>4)*4 + r
  #pragma unroll
  for (int mi = 0; mi < 4; mi++) {
    int rowg = bm * 128 + wr * 64 + mi * 16 + lg * 4;
    #pragma unroll
    for (int ni = 0; ni < 4; ni++) {
      int colg = bn * 128 + wc * 64 + ni * 16 + l15;
      #pragma unroll
      for (int r = 0; r < 4; r++) {
        int rg = rowg + r;
        float v = acc[mi][ni][r];
        if (EPI == 0) {
          int b = rg >> 10, s = rg & 1023;
          int h = colg / 192, c = colg - h * 192;
          int bh = b * 8 + h;
          if (c < 64)
            qws[((size_t)(bh * 1024 + s)) * 64 + c] = f2bf(v * 0.18033688f); // 0.125*log2(e)
          else if (c < 128)
            kws[((size_t)(bh * 1024 + s)) * 64 + (c - 64)] = f2bf(v);
          else
            vtws[((size_t)(bh * 64 + (c - 128))) * 1024 + s] = f2bf(v);
        } else {
          outF[(size_t)rg * 512 + colg] = v;
        }
      }
    }
  }

  if (EPI == 1) {
    float s1 = 0.f, s2 = 0.f;
    #pragma unroll
    for (int mi = 0; mi < 4; mi++)
      #pragma unroll
      for (int ni = 0; ni < 4; ni++)
        #pragma unroll
        for (int r = 0; r < 4; r++) {
          float v = acc[mi][ni][r];
          s1 += v; s2 += v * v;
        }
    #pragma unroll
    for (int off = 1; off < 64; off <<= 1) {
      s1 += __shfl_xor(s1, off);
      s2 += __shfl_xor(s2, off);
    }
    __shared__ float r1[4], r2[4];
    if (lane == 0) { r1[wv] = s1; r2[wv] = s2; }
    __syncthreads();
    if (tid == 0) {
      float t1 = r1[0] + r1[1] + r1[2] + r1[3];
      float t2 = r2[0] + r2[1] + r2[2] + r2[3];
      partials[bm * 4 + bn] = make_float2(t1, t2);
    }
  }
}

// ---------------- Flash attention, swapped-QK^T in-register softmax --------
// grid: 512 blocks = 64 bh * 8 q-tiles of 128 rows; 4 waves * 32 q rows each.
// Logits are in log2 units (Q pre-scaled by 0.125*log2e); exp = v_exp_f32.
__global__ __launch_bounds__(256, 2)
void attn_kernel(const u16* __restrict__ qws, const u16* __restrict__ kws,
                 const u16* __restrict__ vtws, u16* __restrict__ vals)
{
  __shared__ __align__(16) u16 Qsm[128][72];      // Q tile; reused as P after frag hoist
  __shared__ __align__(16) u16 Ksm[2][64][72];    // K dbuf [s][d]
  __shared__ __align__(16) u16 Vsm[2][64][72];    // V dbuf [d][s]
  const int tid = threadIdx.x;
  const int lane = tid & 63;
  const int wv = tid >> 6;
  const int l15 = lane & 15, lg = lane >> 4;
  const int bh = blockIdx.x >> 3;
  const int qt = blockIdx.x & 7;
  const int q0 = qt * 128;

  // ---- prologue: stage Q[128][64], load K/V tile 0 ----
  uint4 qreg[4], kreg[2], vreg[2];
  #pragma unroll
  for (int i = 0; i < 4; i++) {
    int q = tid + i * 256;
    int row = q >> 3, c8 = (q & 7) * 8;
    qreg[i] = *(const uint4*)(qws + ((size_t)bh * 1024 + q0 + row) * 64 + c8);
  }
  #pragma unroll
  for (int i = 0; i < 2; i++) {
    int q = tid + i * 256;
    int row = q >> 3, c8 = (q & 7) * 8;
    kreg[i] = *(const uint4*)(kws + ((size_t)bh * 1024 + row) * 64 + c8);
    vreg[i] = *(const uint4*)(vtws + ((size_t)(bh * 64 + row)) * 1024 + c8);
  }
  #pragma unroll
  for (int i = 0; i < 4; i++) {
    int q = tid + i * 256;
    int row = q >> 3, c8 = (q & 7) * 8;
    *(uint4*)&Qsm[row][c8] = qreg[i];
  }
  __syncthreads();
  // hoist Q B-operand frags (col=q=l15, k-dim=d)
  short8 qf[2][2];
  #pragma unroll
  for (int qi = 0; qi < 2; qi++)
    #pragma unroll
    for (int c = 0; c < 2; c++)
      qf[qi][c] = *(const short8*)&Qsm[wv * 32 + qi * 16 + l15][c * 32 + lg * 8];
  // write K/V tile 0
  #pragma unroll
  for (int i = 0; i < 2; i++) {
    int q = tid + i * 256;
    int row = q >> 3, c8 = (q & 7) * 8;
    *(uint4*)&Ksm[0][row][c8] = kreg[i];
    *(uint4*)&Vsm[0][row][c8] = vreg[i];
  }
  __syncthreads();

  f32x4 o[2][4];
  #pragma unroll
  for (int qi = 0; qi < 2; qi++)
    #pragma unroll
    for (int dn = 0; dn < 4; dn++) o[qi][dn] = (f32x4){0.f, 0.f, 0.f, 0.f};
  float m[2] = {-1e30f, -1e30f}, l[2] = {0.f, 0.f};

  for (int t = 0; t < 16; t++) {
    const int cur = t & 1;
    // T14: issue next-tile loads first; HBM latency hides under compute
    if (t < 15) {
      int kv = (t + 1) * 64;
      #pragma unroll
      for (int i = 0; i < 2; i++) {
        int q = tid + i * 256;
        int row = q >> 3, c8 = (q & 7) * 8;
        kreg[i] = *(const uint4*)(kws + ((size_t)bh * 1024 + kv + row) * 64 + c8);
        vreg[i] = *(const uint4*)(vtws + ((size_t)(bh * 64 + row)) * 1024 + kv + c8);
      }
    }

    // S^T = K * Q^T : C[row=k_local=lg*4+r][col=q=l15]
    f32x4 s[2][4];
    #pragma unroll
    for (int f = 0; f < 4; f++) {
      short8 k0 = *(const short8*)&Ksm[cur][f * 16 + l15][lg * 8];
      short8 k1 = *(const short8*)&Ksm[cur][f * 16 + l15][32 + lg * 8];
      #pragma unroll
      for (int qi = 0; qi < 2; qi++) {
        f32x4 c = (f32x4){0.f, 0.f, 0.f, 0.f};
        c = __builtin_amdgcn_mfma_f32_16x16x32_bf16(k0, qf[qi][0], c, 0, 0, 0);
        c = __builtin_amdgcn_mfma_f32_16x16x32_bf16(k1, qf[qi][1], c, 0, 0, 0);
        s[qi][f] = c;
      }
    }

    // online softmax per qi; lane owns q=l15, k = 16f + lg*4 + r
    #pragma unroll
    for (int qi = 0; qi < 2; qi++) {
      float pm = fmaxf(fmaxf(fmaxf(s[qi][0][0], s[qi][0][1]), fmaxf(s[qi][0][2], s[qi][0][3])),
                       fmaxf(fmaxf(s[qi][1][0], s[qi][1][1]), fmaxf(s[qi][1][2], s[qi][1][3])));
      pm = fmaxf(pm, fmaxf(fmaxf(fmaxf(s[qi][2][0], s[qi][2][1]), fmaxf(s[qi][2][2], s[qi][2][3])),
                           fmaxf(fmaxf(s[qi][3][0], s[qi][3][1]), fmaxf(s[qi][3][2], s[qi][3][3]))));
      pm = fmaxf(pm, __shfl_xor(pm, 16));
      pm = fmaxf(pm, __shfl_xor(pm, 32));
      // T13 defer-max: only rescale when max grew by >10 (log2 units)
      if (!__all(pm - m[qi] <= 10.0f)) {
        float mn = fmaxf(m[qi], pm);
        float al = fast_exp2(m[qi] - mn);
        m[qi] = mn;
        l[qi] *= al;
        #pragma unroll
        for (int r = 0; r < 4; r++) {
          float alo = __shfl(al, lg * 4 + r);   // stats live at lane=q; o rows at lg*4+r
          #pragma unroll
          for (int dn = 0; dn < 4; dn++) o[qi][dn][r] *= alo;
        }
      }
      float rs = 0.f;
      unsigned pk[4][2];
      #pragma unroll
      for (int f = 0; f < 4; f++) {
        float p0 = fast_exp2(s[qi][f][0] - m[qi]);
        float p1 = fast_exp2(s[qi][f][1] - m[qi]);
        float p2 = fast_exp2(s[qi][f][2] - m[qi]);
        float p3 = fast_exp2(s[qi][f][3] - m[qi]);
        rs += (p0 + p1) + (p2 + p3);
        pk[f][0] = cvt_pk_bf16(p0, p1);
        pk[f][1] = cvt_pk_bf16(p2, p3);
      }
      rs += __shfl_xor(rs, 16);
      rs += __shfl_xor(rs, 32);
      l[qi] += rs;
      // P -> LDS (Q region, wave-private rows), vectorized b64
      #pragma unroll
      for (int f = 0; f < 4; f++)
        *(uint2*)(&Qsm[wv * 32 + qi * 16 + l15][0] + 16 * f + 4 * lg) = make_uint2(pk[f][0], pk[f][1]);
    }

    // O += P * V : A = P[16q x 32k] (row=q=l15), B = Vt (col=d=l15)
    short8 pa[2][2];
    #pragma unroll
    for (int qi = 0; qi < 2; qi++) {
      pa[qi][0] = *(const short8*)&Qsm[wv * 32 + qi * 16 + l15][lg * 8];
      pa[qi][1] = *(const short8*)&Qsm[wv * 32 + qi * 16 + l15][32 + lg * 8];
    }
    #pragma unroll
    for (int dn = 0; dn < 4; dn++) {
      short8 v0 = *(const short8*)&Vsm[cur][dn * 16 + l15][lg * 8];
      short8 v1 = *(const short8*)&Vsm[cur][dn * 16 + l15][32 + lg * 8];
      #pragma unroll
      for (int qi = 0; qi < 2; qi++) {
        o[qi][dn] = __builtin_amdgcn_mfma_f32_16x16x32_bf16(pa[qi][0], v0, o[qi][dn], 0, 0, 0);
        o[qi][dn] = __builtin_amdgcn_mfma_f32_16x16x32_bf16(pa[qi][1], v1, o[qi][dn], 0, 0, 0);
      }
    }

    // write next tile to the other buffer
    if (t < 15) {
      #pragma unroll
      for (int i = 0; i < 2; i++) {
        int q = tid + i * 256;
        int row = q >> 3, c8 = (q & 7) * 8;
        *(uint4*)&Ksm[cur ^ 1][row][c8] = kreg[i];
        *(uint4*)&Vsm[cur ^ 1][row][c8] = vreg[i];
      }
    }
    __syncthreads();
  }

  // epilogue: vals[b, s, h*64+d] bf16
  const int b = bh >> 3, h = bh & 7;
  #pragma unroll
  for (int qi = 0; qi < 2; qi++) {
    #pragma unroll
    for (int r = 0; r < 4; r++) {
      float lo = __shfl(l[qi], lg * 4 + r);
      float inv = 1.0f / lo;
      int qrow = q0 + wv * 32 + qi * 16 + lg * 4 + r;
      #pragma unroll
      for (int dn = 0; dn < 4; dn++) {
        int col = h * 64 + dn * 16 + l15;
        vals[((size_t)(b * 1024 + qrow)) * 512 + col] = f2bf(o[qi][dn][r] * inv);
      }
    }
  }
}

// ---------------- LN finalize: reduce 32 partials per batch ----------------
__global__ void ln_fin(const float2* __restrict__ partials, float* __restrict__ stats) {
  const int b = blockIdx.x;      // 8 blocks, 64 threads
  const int t = threadIdx.x;
  float s1 = 0.f, s2 = 0.f;
  if (t < 32) {
    float2 p = partials[b * 32 + t];
    s1 = p.x; s2 = p.y;
  }
  #pragma unroll
  for (int off = 1; off < 64; off <<= 1) {
    s1 += __shfl_xor(s1, off);
    s2 += __shfl_xor(s2, off);
  }
  if (t == 0) {
    float mu = s1 / 524288.f;
    float var = s2 / 524288.f - mu * mu;
    stats[b * 2] = mu;
    stats[b * 2 + 1] = rsqrtf(var + 1e-5f);
  }
}

__global__ void ln_norm(float* __restrict__ o, const float* __restrict__ stats) {
  int i = blockIdx.x * blockDim.x + threadIdx.x;
  int stride = gridDim.x * blockDim.x;
  for (; i < 1048576; i += stride) {
    int b = i >> 17;  // 131072 float4 per batch
    float mu = stats[b * 2], rs = stats[b * 2 + 1];
    float4 v = ((float4*)o)[i];
    v.x = (v.x - mu) * rs; v.y = (v.y - mu) * rs;
    v.z = (v.z - mu) * rs; v.w = (v.w - mu) * rs;
    ((float4*)o)[i] = v;
  }
}

extern "C" void kernel_launch(void* const* d_in, const int* in_sizes, int n_in,
                              void* d_out, int out_size, void* d_ws, size_t ws_size,
                              hipStream_t stream) {
  const float* x = (const float*)d_in[0];
  const float* wqkv = (const float*)d_in[1];
  const float* wo = (const float*)d_in[2];
  float* out = (float*)d_out;
  char* ws = (char*)d_ws;

  u16* xb        = (u16*)(ws + 0);          // 8192*512   bf16 =  8,388,608 B
  u16* wqb       = (u16*)(ws + 8388608);    // 1536*512   bf16 =  1,572,864 B
  u16* wob       = (u16*)(ws + 9961472);    // 512*512    bf16 =    524,288 B
  u16* qws       = (u16*)(ws + 10485760);   // [bh,1024,64]    =  8,388,608 B
  u16* kws       = (u16*)(ws + 18874368);   // [bh,1024,64]    =  8,388,608 B
  u16* vtws      = (u16*)(ws + 27262976);   // [bh,64,1024]    =  8,388,608 B
  u16* vals      = (u16*)(ws + 35651584);   // [8192,512] bf16 =  8,388,608 B
  float* st      = (float*)(ws + 44040192); // 16 floats
  float2* parts  = (float2*)(ws + 44040256);// 256 float2 = 2 KB

  cvt_all<<<1280, 256, 0, stream>>>(x, wqkv, wo, xb, wqb, wob);

  dim3 g1(64, 12);
  gemm_nt<0><<<g1, 256, 0, stream>>>(xb, wqb, 512, nullptr, qws, kws, vtws, nullptr);

  attn_kernel<<<512, 256, 0, stream>>>(qws, kws, vtws, vals);

  dim3 g2(64, 4);
  gemm_nt<1><<<g2, 256, 0, stream>>>(vals, wob, 512, out, nullptr, nullptr, nullptr, parts);

  ln_fin<<<8, 64, 0, stream>>>(parts, st);
  ln_norm<<<2048, 256, 0, stream>>>(out, st);
}

// Round 4
// 90.557 us; speedup vs baseline: 3.1484x; 1.2139x over previous
//
#include <hip/hip_runtime.h>
#include <hip/hip_bf16.h>
#include <math.h>

// Problem constants
#define BB 8
#define SS 1024
#define INDIM 512
#define ED 512
#define NH 8
#define HD 64

typedef __attribute__((ext_vector_type(8))) short short8;
typedef __attribute__((ext_vector_type(4))) float f32x4;
typedef __attribute__((ext_vector_type(16))) float f32x16;
typedef unsigned short u16;

static __device__ __forceinline__ u16 f2bf(float f) {
  union { float f; unsigned u; } v; v.f = f;
  unsigned r = v.u + 0x7fffu + ((v.u >> 16) & 1u);
  return (u16)(r >> 16);
}

// packed f32x2 -> bf16x2 (RTNE), single VOP3 instr on gfx950
static __device__ __forceinline__ unsigned cvt_pk_bf16(float a, float b) {
  unsigned r;
  asm("v_cvt_pk_bf16_f32 %0, %1, %2" : "=v"(r) : "v"(a), "v"(b));
  return r;
}
// v_exp_f32 = 2^x natively
static __device__ __forceinline__ float fast_exp2(float x) {
  float r; asm("v_exp_f32 %0, %1" : "=v"(r) : "v"(x)); return r;
}

// ---------------- fp32 -> bf16 convert (all three inputs, one launch) ------
__global__ void cvt_all(const float* __restrict__ x, const float* __restrict__ wq,
                        const float* __restrict__ wo, u16* __restrict__ xb,
                        u16* __restrict__ wqb, u16* __restrict__ wob) {
  const int n1 = 1048576;            // x: 4194304/4 quads
  const int n2 = n1 + 196608;        // wqkv: 786432/4
  const int n3 = n2 + 65536;         // wo: 262144/4
  int i = blockIdx.x * blockDim.x + threadIdx.x;
  int stride = gridDim.x * blockDim.x;
  for (; i < n3; i += stride) {
    const float4* src; ushort4* dst; int j;
    if (i < n1)      { src = (const float4*)x;  dst = (ushort4*)xb;  j = i; }
    else if (i < n2) { src = (const float4*)wq; dst = (ushort4*)wqb; j = i - n1; }
    else             { src = (const float4*)wo; dst = (ushort4*)wob; j = i - n2; }
    float4 v = src[j];
    ushort4 o;
    o.x = f2bf(v.x); o.y = f2bf(v.y); o.z = f2bf(v.z); o.w = f2bf(v.w);
    dst[j] = o;
  }
}

// ---------------- NT GEMM: C[M,N] = A[M,K] * B[N,K]^T (bf16 in, MFMA) -------
// EPI==0: QKV projection epilogue -> scatter to q (x 0.125*log2e), k, vt layouts
// EPI==1: fp32 output (O projection) + per-block LN partial stats
template<int EPI>
__global__ __launch_bounds__(256, 2)
void gemm_nt(const u16* __restrict__ A, const u16* __restrict__ Bm, int K,
             float* __restrict__ outF,
             u16* __restrict__ qws, u16* __restrict__ kws, u16* __restrict__ vtws,
             float2* __restrict__ partials)
{
  __shared__ u16 As[128][72];
  __shared__ u16 Bs[128][72];
  const int tid = threadIdx.x;
  const int lane = tid & 63;
  const int wv = tid >> 6;
  const int wr = wv >> 1, wc = wv & 1;
  const int bm = blockIdx.x, bn = blockIdx.y;
  const int l15 = lane & 15, lg = lane >> 4;

  f32x4 acc[4][4];
  #pragma unroll
  for (int i = 0; i < 4; i++)
    #pragma unroll
    for (int j = 0; j < 4; j++) acc[i][j] = (f32x4){0.f, 0.f, 0.f, 0.f};

  for (int kk = 0; kk < K; kk += 64) {
    #pragma unroll
    for (int t = 0; t < 4; t++) {
      int ci = tid + t * 256;
      int row = ci >> 3, col = (ci & 7) * 8;
      uint4 va = *(const uint4*)(A + (size_t)(bm * 128 + row) * K + kk + col);
      *(uint4*)&As[row][col] = va;
      uint4 vb = *(const uint4*)(Bm + (size_t)(bn * 128 + row) * K + kk + col);
      *(uint4*)&Bs[row][col] = vb;
    }
    __syncthreads();
    #pragma unroll
    for (int kc = 0; kc < 2; kc++) {
      short8 af[4], bf[4];
      #pragma unroll
      for (int mi = 0; mi < 4; mi++)
        af[mi] = *(const short8*)&As[wr * 64 + mi * 16 + l15][kc * 32 + lg * 8];
      #pragma unroll
      for (int ni = 0; ni < 4; ni++)
        bf[ni] = *(const short8*)&Bs[wc * 64 + ni * 16 + l15][kc * 32 + lg * 8];
      #pragma unroll
      for (int mi = 0; mi < 4; mi++)
        #pragma unroll
        for (int ni = 0; ni < 4; ni++)
          acc[mi][ni] = __builtin_amdgcn_mfma_f32_16x16x32_bf16(af[mi], bf[ni], acc[mi][ni], 0, 0, 0);
    }
    __syncthreads();
  }

  // epilogue; C-frag: col = lane&15, row = (lane>>4)*4 + r
  #pragma unroll
  for (int mi = 0; mi < 4; mi++) {
    int rowg = bm * 128 + wr * 64 + mi * 16 + lg * 4;
    #pragma unroll
    for (int ni = 0; ni < 4; ni++) {
      int colg = bn * 128 + wc * 64 + ni * 16 + l15;
      #pragma unroll
      for (int r = 0; r < 4; r++) {
        int rg = rowg + r;
        float v = acc[mi][ni][r];
        if (EPI == 0) {
          int b = rg >> 10, s = rg & 1023;
          int h = colg / 192, c = colg - h * 192;
          int bh = b * 8 + h;
          if (c < 64)
            qws[((size_t)(bh * 1024 + s)) * 64 + c] = f2bf(v * 0.18033688f); // 0.125*log2(e)
          else if (c < 128)
            kws[((size_t)(bh * 1024 + s)) * 64 + (c - 64)] = f2bf(v);
          else
            vtws[((size_t)(bh * 64 + (c - 128))) * 1024 + s] = f2bf(v);
        } else {
          outF[(size_t)rg * 512 + colg] = v;
        }
      }
    }
  }

  if (EPI == 1) {
    float s1 = 0.f, s2 = 0.f;
    #pragma unroll
    for (int mi = 0; mi < 4; mi++)
      #pragma unroll
      for (int ni = 0; ni < 4; ni++)
        #pragma unroll
        for (int r = 0; r < 4; r++) {
          float v = acc[mi][ni][r];
          s1 += v; s2 += v * v;
        }
    #pragma unroll
    for (int off = 1; off < 64; off <<= 1) {
      s1 += __shfl_xor(s1, off);
      s2 += __shfl_xor(s2, off);
    }
    __shared__ float r1[4], r2[4];
    if (lane == 0) { r1[wv] = s1; r2[wv] = s2; }
    __syncthreads();
    if (tid == 0) {
      float t1 = r1[0] + r1[1] + r1[2] + r1[3];
      float t2 = r2[0] + r2[1] + r2[2] + r2[3];
      partials[bm * 4 + bn] = make_float2(t1, t2);
    }
  }
}

// ---------------- Flash attention, 32x32 swapped-QK^T, register-only P -----
// Logical grid: 64 bh * 8 q-tiles of 128; XCD-swizzled so one bh stays on one
// XCD (K/V served from its L2). 4 waves * 32 q rows. Logits in log2 units.
__global__ __launch_bounds__(256, 2)
void attn_kernel(const u16* __restrict__ qws, const u16* __restrict__ kws,
                 const u16* __restrict__ vtws, u16* __restrict__ vals)
{
  __shared__ __align__(16) u16 Ksm[2][64][72];   // K tile [k][d], dbuf
  __shared__ __align__(16) u16 Vsm[2][64][72];   // V tile [d][k], dbuf
  const int tid = threadIdx.x;
  const int lane = tid & 63;
  const int wq = tid >> 6;          // wave id, 32 q rows each
  const int l31 = lane & 31;
  const int hi = lane >> 5;
  // XCD swizzle: blocks 8i..8i+7 (HW round-robin over XCDs) -> logical chunks
  const int logical = (blockIdx.x & 7) * 64 + (blockIdx.x >> 3);
  const int bh = logical >> 3;
  const int q0 = (logical & 7) * 128;

  // ---- Q B-frags from global: col=q=l31, k-dim d = 16j+8hi+e ----
  short8 qf[4];
  {
    const u16* qp = qws + ((size_t)bh * 1024 + q0 + wq * 32 + l31) * 64 + 8 * hi;
    #pragma unroll
    for (int j = 0; j < 4; j++) qf[j] = *(const short8*)(qp + 16 * j);
  }

  // ---- stage K/V tile 0 ----
  const int srow = tid >> 3;             // 0..31
  const int sc8 = (tid & 7) * 8;
  uint4 kreg[2], vreg[2];
  {
    kreg[0] = *(const uint4*)(kws + ((size_t)bh * 1024 + srow) * 64 + sc8);
    kreg[1] = *(const uint4*)(kws + ((size_t)bh * 1024 + srow + 32) * 64 + sc8);
    vreg[0] = *(const uint4*)(vtws + ((size_t)(bh * 64 + srow)) * 1024 + sc8);
    vreg[1] = *(const uint4*)(vtws + ((size_t)(bh * 64 + srow + 32)) * 1024 + sc8);
    *(uint4*)&Ksm[0][srow][sc8] = kreg[0];
    *(uint4*)&Ksm[0][srow + 32][sc8] = kreg[1];
    *(uint4*)&Vsm[0][srow][sc8] = vreg[0];
    *(uint4*)&Vsm[0][srow + 32][sc8] = vreg[1];
  }
  __syncthreads();

  f32x16 o[2];
  #pragma unroll
  for (int r = 0; r < 16; r++) { o[0][r] = 0.f; o[1][r] = 0.f; }
  float m = -1e30f, l = 0.f;

  for (int t = 0; t < 16; t++) {
    const int cur = t & 1;
    // T14: issue next-tile global loads first
    if (t < 15) {
      int kv = (t + 1) * 64;
      kreg[0] = *(const uint4*)(kws + ((size_t)bh * 1024 + kv + srow) * 64 + sc8);
      kreg[1] = *(const uint4*)(kws + ((size_t)bh * 1024 + kv + srow + 32) * 64 + sc8);
      vreg[0] = *(const uint4*)(vtws + ((size_t)(bh * 64 + srow)) * 1024 + kv + sc8);
      vreg[1] = *(const uint4*)(vtws + ((size_t)(bh * 64 + srow + 32)) * 1024 + kv + sc8);
    }

    // ---- S^T = K * Q^T: C[row=k_local][col=q=l31] per 32-key subtile ----
    f32x16 stv[2];
    #pragma unroll
    for (int s2 = 0; s2 < 2; s2++) {
      f32x16 c;
      #pragma unroll
      for (int r = 0; r < 16; r++) c[r] = 0.f;
      #pragma unroll
      for (int j = 0; j < 4; j++) {
        short8 kf = *(const short8*)&Ksm[cur][s2 * 32 + l31][16 * j + 8 * hi];
        c = __builtin_amdgcn_mfma_f32_32x32x16_bf16(kf, qf[j], c, 0, 0, 0);
      }
      stv[s2] = c;
    }

    // ---- online softmax: lane owns q=l31, 32 of 64 k's (other half at lane^32)
    float mx[16];
    #pragma unroll
    for (int r = 0; r < 16; r++) mx[r] = fmaxf(stv[0][r], stv[1][r]);
    #pragma unroll
    for (int w = 8; w >= 1; w >>= 1)
      #pragma unroll
      for (int r = 0; r < w; r++) mx[r] = fmaxf(mx[r], mx[r + w]);
    float pm = fmaxf(mx[0], __shfl_xor(mx[0], 32));

    // T13 defer-max (log2 units)
    if (!__all(pm - m <= 10.0f)) {
      float mn = fmaxf(m, pm);
      float al = fast_exp2(m - mn);
      m = mn; l *= al;
      #pragma unroll
      for (int reg = 0; reg < 16; reg++) {
        int qrow = (reg & 3) + 8 * (reg >> 2) + 4 * hi;
        float alo = __shfl(al, qrow);
        o[0][reg] *= alo; o[1][reg] *= alo;
      }
    }

    unsigned pk[16];
    float ps[16];
    #pragma unroll
    for (int s2 = 0; s2 < 2; s2++)
      #pragma unroll
      for (int j = 0; j < 8; j++) {
        float p0 = fast_exp2(stv[s2][2 * j] - m);
        float p1 = fast_exp2(stv[s2][2 * j + 1] - m);
        ps[s2 * 8 + j] = p0 + p1;
        pk[s2 * 8 + j] = cvt_pk_bf16(p0, p1);
      }
    #pragma unroll
    for (int w = 8; w >= 1; w >>= 1)
      #pragma unroll
      for (int r = 0; r < w; r++) ps[r] += ps[r + w];
    l += ps[0] + __shfl_xor(ps[0], 32);

    // ---- P redistribution: 8 permlane32_swap build PV A-frags in-register ----
    short8 pa[4];
    #pragma unroll
    for (int cc = 0; cc < 4; cc++) {
      int base = (cc >> 1) * 8 + (cc & 1) * 4;
      unsigned a0 = pk[base + 0], a2 = pk[base + 2];
      unsigned a1 = pk[base + 1], a3 = pk[base + 3];
      asm volatile("v_permlane32_swap_b32 %0, %1" : "+v"(a0), "+v"(a2));
      asm volatile("v_permlane32_swap_b32 %0, %1" : "+v"(a1), "+v"(a3));
      union { unsigned u[4]; short8 s8; } uu;
      uu.u[0] = a0; uu.u[1] = a1; uu.u[2] = a2; uu.u[3] = a3;
      pa[cc] = uu.s8;
    }

    // ---- O += P * V : A=P[q][k], B=V[k][d] (from Vt rows) ----
    #pragma unroll
    for (int dh = 0; dh < 2; dh++)
      #pragma unroll
      for (int cc = 0; cc < 4; cc++) {
        short8 vf = *(const short8*)&Vsm[cur][dh * 32 + l31][16 * cc + 8 * hi];
        o[dh] = __builtin_amdgcn_mfma_f32_32x32x16_bf16(pa[cc], vf, o[dh], 0, 0, 0);
      }

    // ---- write next tile into other buffer ----
    if (t < 15) {
      *(uint4*)&Ksm[cur ^ 1][srow][sc8] = kreg[0];
      *(uint4*)&Ksm[cur ^ 1][srow + 32][sc8] = kreg[1];
      *(uint4*)&Vsm[cur ^ 1][srow][sc8] = vreg[0];
      *(uint4*)&Vsm[cur ^ 1][srow + 32][sc8] = vreg[1];
    }
    __syncthreads();
  }

  // ---- epilogue: vals[b, s, h*64+d] bf16 ----
  const int b = bh >> 3, h = bh & 7;
  #pragma unroll
  for (int reg = 0; reg < 16; reg++) {
    int qrow = (reg & 3) + 8 * (reg >> 2) + 4 * hi;
    float linv = 1.0f / __shfl(l, qrow);
    size_t grow = (size_t)(b * 1024 + q0 + wq * 32 + qrow) * 512 + h * 64;
    vals[grow + l31]      = f2bf(o[0][reg] * linv);
    vals[grow + 32 + l31] = f2bf(o[1][reg] * linv);
  }
}

// ---------------- LN finalize: reduce 32 partials per batch ----------------
__global__ void ln_fin(const float2* __restrict__ partials, float* __restrict__ stats) {
  const int b = blockIdx.x;      // 8 blocks, 64 threads
  const int t = threadIdx.x;
  float s1 = 0.f, s2 = 0.f;
  if (t < 32) {
    float2 p = partials[b * 32 + t];
    s1 = p.x; s2 = p.y;
  }
  #pragma unroll
  for (int off = 1; off < 64; off <<= 1) {
    s1 += __shfl_xor(s1, off);
    s2 += __shfl_xor(s2, off);
  }
  if (t == 0) {
    float mu = s1 / 524288.f;
    float var = s2 / 524288.f - mu * mu;
    stats[b * 2] = mu;
    stats[b * 2 + 1] = rsqrtf(var + 1e-5f);
  }
}

__global__ void ln_norm(float* __restrict__ o, const float* __restrict__ stats) {
  int i = blockIdx.x * blockDim.x + threadIdx.x;
  int stride = gridDim.x * blockDim.x;
  for (; i < 1048576; i += stride) {
    int b = i >> 17;  // 131072 float4 per batch
    float mu = stats[b * 2], rs = stats[b * 2 + 1];
    float4 v = ((float4*)o)[i];
    v.x = (v.x - mu) * rs; v.y = (v.y - mu) * rs;
    v.z = (v.z - mu) * rs; v.w = (v.w - mu) * rs;
    ((float4*)o)[i] = v;
  }
}

extern "C" void kernel_launch(void* const* d_in, const int* in_sizes, int n_in,
                              void* d_out, int out_size, void* d_ws, size_t ws_size,
                              hipStream_t stream) {
  const float* x = (const float*)d_in[0];
  const float* wqkv = (const float*)d_in[1];
  const float* wo = (const float*)d_in[2];
  float* out = (float*)d_out;
  char* ws = (char*)d_ws;

  u16* xb        = (u16*)(ws + 0);          // 8192*512   bf16 =  8,388,608 B
  u16* wqb       = (u16*)(ws + 8388608);    // 1536*512   bf16 =  1,572,864 B
  u16* wob       = (u16*)(ws + 9961472);    // 512*512    bf16 =    524,288 B
  u16* qws       = (u16*)(ws + 10485760);   // [bh,1024,64]    =  8,388,608 B
  u16* kws       = (u16*)(ws + 18874368);   // [bh,1024,64]    =  8,388,608 B
  u16* vtws      = (u16*)(ws + 27262976);   // [bh,64,1024]    =  8,388,608 B
  u16* vals      = (u16*)(ws + 35651584);   // [8192,512] bf16 =  8,388,608 B
  float* st      = (float*)(ws + 44040192); // 16 floats
  float2* parts  = (float2*)(ws + 44040256);// 256 float2 = 2 KB

  cvt_all<<<1280, 256, 0, stream>>>(x, wqkv, wo, xb, wqb, wob);

  dim3 g1(64, 12);
  gemm_nt<0><<<g1, 256, 0, stream>>>(xb, wqb, 512, nullptr, qws, kws, vtws, nullptr);

  attn_kernel<<<512, 256, 0, stream>>>(qws, kws, vtws, vals);

  dim3 g2(64, 4);
  gemm_nt<1><<<g2, 256, 0, stream>>>(vals, wob, 512, out, nullptr, nullptr, nullptr, parts);

  ln_fin<<<8, 64, 0, stream>>>(parts, st);
  ln_norm<<<2048, 256, 0, stream>>>(out, st);
}